// Round 2
// baseline (94.253 us; speedup 1.0000x reference)
//
#include <hip/hip_runtime.h>

#define DM 2048
#define BB 64
#define SS 32
#define CC 8

// Interleaved-transposed A layout ("a4"): a4[(k>>2)*256 + b*4 + (k&3)] = A[b][k]
// A wave load of float4 at (k4*256 + lane*4) yields lane=b, k = k4*4..k4*4+3.

// K1: ut4 = sum_c controls[c][b][k], written in a4 layout.
// grid 256 (b*4 + kchunk), block 128
__global__ void k1_sum_transpose(const float* __restrict__ controls,
                                 float* __restrict__ ut4) {
  const int b = blockIdx.x >> 2;
  const int k = (blockIdx.x & 3) * 512 + threadIdx.x * 4;
  float4 s = make_float4(0.f, 0.f, 0.f, 0.f);
#pragma unroll
  for (int c = 0; c < CC; ++c) {
    const float4 v = *reinterpret_cast<const float4*>(
        controls + ((size_t)c * BB + b) * DM + k);
    s.x += v.x; s.y += v.y; s.z += v.z; s.w += v.w;
  }
  *reinterpret_cast<float4*>(ut4 + (k >> 2) * 256 + b * 4) = s;
}

// GEMM with 32-way k-split (8 block-level kp x 4 waves), block-level LDS reduce.
// C[e][b] = sum_k W[e][k] * A[b][k];  A in a4 layout.
// grid 2048: eg = blockIdx & 255 (8 e each), kp = blockIdx >> 8 (0..7)
// wave wv takes k-range [kp*256 + wv*64, +64)
// TR=0: part[kp][e][b] (for reduce_to_a4)   TR=1: part[kp][b][e] (for reduce_to_pt)
template <int TR>
__global__ void gemm_ksplit(const float* __restrict__ a4,
                            const float* __restrict__ w,
                            float* __restrict__ part) {
  const int lane = threadIdx.x & 63;
  const int wv   = threadIdx.x >> 6;
  const int e0   = (blockIdx.x & 255) * 8;
  const int kp   = blockIdx.x >> 8;
  const int k0   = kp * 256 + wv * 64;

  float acc[8] = {0.f, 0.f, 0.f, 0.f, 0.f, 0.f, 0.f, 0.f};
  const float4* ab =
      reinterpret_cast<const float4*>(a4 + (size_t)(k0 >> 2) * 256) + lane;
  const float* wb = w + (size_t)e0 * DM + k0;

#pragma unroll 2
  for (int kq = 0; kq < 16; ++kq) {
    const float4 a = ab[kq * 64];
#pragma unroll
    for (int j = 0; j < 8; ++j) {
      const float4 ww =
          *reinterpret_cast<const float4*>(wb + (size_t)j * DM + kq * 4);
      acc[j] += a.x * ww.x + a.y * ww.y + a.z * ww.z + a.w * ww.w;
    }
  }

  __shared__ float red[4][8][64];
#pragma unroll
  for (int j = 0; j < 8; ++j) red[wv][j][lane] = acc[j];
  __syncthreads();

  if (TR == 0) {
    const int t = threadIdx.x;
#pragma unroll
    for (int o = t; o < 512; o += 256) {
      const int j = o >> 6, b = o & 63;
      const float v = red[0][j][b] + red[1][j][b] + red[2][j][b] + red[3][j][b];
      part[((size_t)kp * DM + e0 + j) * 64 + b] = v;
    }
  } else {
    const int t  = threadIdx.x;
    const int b  = t >> 2;
    const int jj = (t & 3) * 2;
    const float v0 =
        red[0][jj][b] + red[1][jj][b] + red[2][jj][b] + red[3][jj][b];
    const float v1 = red[0][jj + 1][b] + red[1][jj + 1][b] +
                     red[2][jj + 1][b] + red[3][jj + 1][b];
    *reinterpret_cast<float2*>(part + ((size_t)kp * 64 + b) * DM + e0 + jj) =
        make_float2(v0, v1);
  }
}

// R1: a4out[(e>>2)*256 + b*4 + (e&3)] = sum_kp part[kp][e][b] + 8*bias[e]
// grid 512, block 64
__global__ void reduce_to_a4(const float* __restrict__ part,
                             const float* __restrict__ bias,
                             float* __restrict__ out4) {
  const int idx = blockIdx.x * 64 + threadIdx.x;  // 32768
  const int b = idx & 63, eq = idx >> 6;
  float s[4];
#pragma unroll
  for (int i = 0; i < 4; ++i) {
    const int e = eq * 4 + i;
    float v = 8.0f * bias[e];
#pragma unroll
    for (int kp = 0; kp < 8; ++kp)
      v += part[((size_t)kp * DM + e) * 64 + b];
    s[i] = v;
  }
  *reinterpret_cast<float4*>(out4 + eq * 256 + b * 4) =
      make_float4(s[0], s[1], s[2], s[3]);
}

// R2: pt2[b][e] = sum_kp part_t[kp][b][e] + 8*bias[e]
// grid 512, block 256 (idx = b*2048 + e)
__global__ void reduce_to_pt(const float* __restrict__ part_t,
                             const float* __restrict__ bias,
                             float* __restrict__ pt2) {
  const int idx = blockIdx.x * 256 + threadIdx.x;  // 131072
  const int e = idx & 2047;
  const int b = idx >> 11;
  float v = 8.0f * bias[e];
#pragma unroll
  for (int kp = 0; kp < 8; ++kp)
    v += part_t[((size_t)kp * 64 + b) * DM + e];
  pt2[idx] = v;
}

// K4: out[b][s][e] = seq[b][s][e] + pt2[b][e]
// grid 2048: b = bi>>5, s0 = ((bi>>1)&15)*2, e0 = (bi&1)*1024; block 256
__global__ void k4_broadcast_add(const float* __restrict__ seq,
                                 const float* __restrict__ pt2,
                                 float* __restrict__ out) {
  const int bi = blockIdx.x;
  const int b  = bi >> 5;
  const int s0 = ((bi >> 1) & 15) * 2;
  const int e  = (bi & 1) * 1024 + threadIdx.x * 4;
  const float4 pv = *reinterpret_cast<const float4*>(pt2 + (size_t)b * DM + e);
  const size_t base = ((size_t)b * SS + s0) * DM + e;
  const float4 q0 = *reinterpret_cast<const float4*>(seq + base);
  const float4 q1 = *reinterpret_cast<const float4*>(seq + base + DM);
  *reinterpret_cast<float4*>(out + base) =
      make_float4(q0.x + pv.x, q0.y + pv.y, q0.z + pv.z, q0.w + pv.w);
  *reinterpret_cast<float4*>(out + base + DM) =
      make_float4(q1.x + pv.x, q1.y + pv.y, q1.z + pv.z, q1.w + pv.w);
}

extern "C" void kernel_launch(void* const* d_in, const int* in_sizes, int n_in,
                              void* d_out, int out_size, void* d_ws,
                              size_t ws_size, hipStream_t stream) {
  const float* seq      = (const float*)d_in[0];
  const float* controls = (const float*)d_in[1];
  // d_in[2..5] = Wq, bq, Wk, bk — mathematically unused (softmax over size-1 axis == 1)
  const float* Wv = (const float*)d_in[6];
  const float* bv = (const float*)d_in[7];
  const float* Wo = (const float*)d_in[8];
  const float* bo = (const float*)d_in[9];
  float* out = (float*)d_out;

  char* ws = (char*)d_ws;
  float* ut4  = (float*)(ws);                    // 512 KB
  float* vt4  = (float*)(ws + (512ull << 10));   // 512 KB
  float* pt2  = (float*)(ws + (1024ull << 10));  // 512 KB  [64][2048]
  float* part = (float*)(ws + (1536ull << 10));  // 4 MB    [8][2048][64] or [8][64][2048]

  k1_sum_transpose<<<256, 128, 0, stream>>>(controls, ut4);
  gemm_ksplit<0><<<2048, 256, 0, stream>>>(ut4, Wv, part);
  reduce_to_a4<<<512, 64, 0, stream>>>(part, bv, vt4);
  gemm_ksplit<1><<<2048, 256, 0, stream>>>(vt4, Wo, part);
  reduce_to_pt<<<512, 256, 0, stream>>>(part, bo, pt2);
  k4_broadcast_add<<<2048, 256, 0, stream>>>(seq, pt2, out);
}